// Round 14
// baseline (837.061 us; speedup 1.0000x reference)
//
#include <hip/hip_runtime.h>
#include <hip/hip_bf16.h>
#include <stdint.h>

#define B_  2048
#define T_  16
#define F_  768
#define H_  1024
#define G4_ 4096   // 4*H

typedef __attribute__((ext_vector_type(8))) __bf16 bf16x8;
typedef __attribute__((ext_vector_type(4))) float  f32x4;

static __device__ __forceinline__ unsigned short f2bf(float f) {
    union { float f; uint32_t u; } v; v.f = f;
    uint32_t u = v.u;
    uint32_t r = (u + 0x7fffu + ((u >> 16) & 1u)) >> 16;   // RNE
    return (unsigned short)r;
}
static __device__ __forceinline__ unsigned short f2h(float f) {
    union { _Float16 h; unsigned short u; } v; v.h = (_Float16)f; return v.u;
}
static __device__ __forceinline__ float h2f(unsigned short u) {
    union { _Float16 h; unsigned short u; } v; v.u = u; return (float)v.h;
}
static __device__ __forceinline__ float sigf(float x) {
    return 1.0f / (1.0f + __expf(-x));
}
static __device__ __forceinline__ float tanhfast(float x) {
    return 2.0f / (1.0f + __expf(-2.0f * x)) - 1.0f;
}

#define GLOAD_LDS16(gsrc, ldst)                                                       \
    __builtin_amdgcn_global_load_lds((const __attribute__((address_space(1))) void*)(gsrc), \
                                     (__attribute__((address_space(3))) void*)(ldst), \
                                     16, 0, 0)

// ---------------------------------------------------------------- merged prep kernel
// (round-13 verbatim)

__global__ void prep_kernel(const float* __restrict__ x, unsigned short* __restrict__ xbf,
                            const float* __restrict__ Wih, unsigned short* __restrict__ wih_t,
                            const float* __restrict__ Whh, unsigned short* __restrict__ whh_t) {
    const int bid = blockIdx.x;
    const int tid = threadIdx.x;
    if (bid < 24576) {
        int idx = bid * 256 + tid;      // B*T*F/4 float4
        float4 v = *(const float4*)(x + (size_t)idx * 4);
        ushort4 o;
        o.x = f2bf(v.x); o.y = f2bf(v.y); o.z = f2bf(v.z); o.w = f2bf(v.w);
        *(ushort4*)(xbf + (size_t)idx * 4) = o;
        return;
    }
    __shared__ float tile[32][33];
    const float* w;
    unsigned short* wt;
    int K, mode, idx;
    if (bid < 24576 + 3072) { w = Wih; wt = wih_t; K = F_; mode = 0; idx = bid - 24576; }
    else                    { w = Whh; wt = whh_t; K = H_; mode = 1; idx = bid - 27648; }
    int nb = (idx & 127) * 32;          // over 4096
    int kb = (idx >> 7) * 32;           // over K
    int tx = tid & 31, ty = tid >> 5;   // 32 x 8
    #pragma unroll
    for (int i = 0; i < 32; i += 8)
        tile[ty + i][tx] = w[(size_t)(kb + ty + i) * G4_ + nb + tx];
    __syncthreads();
    #pragma unroll
    for (int i = 0; i < 32; i += 8) {
        int n = nb + ty + i;
        int g = n >> 10;
        int j = n & 1023;
        int np = mode ? ((j >> 4) * 64 + g * 16 + (j & 15))
                      : ((j >> 6) * 256 + g * 64 + ((j >> 4) & 3) * 16 + (j & 15));
        wt[(size_t)np * K + kb + tx] = f2bf(tile[tx][ty + i]);
    }
}

// ================================================================ 8-phase 256^2 xgemm, M-merged x4
// (round-13 verbatim; measured 219 us @ MfmaUtil 41%)

#define STAGE4(bufi, kind, half, gbase, ld, rowbase, kt) do {                         \
    const int kel_ = (kt) * 64;                                                       \
    _Pragma("unroll")                                                                 \
    for (int r2 = 0; r2 < 2; ++r2) {                                                  \
        const int rih_ = r2 * 64 + (tid >> 3);                                        \
        const int ch_  = (tid & 7) ^ (rih_ & 7);                                      \
        GLOAD_LDS16((gbase) + (size_t)((rowbase) + (half) * 128 + rih_) * (ld)        \
                            + kel_ + ch_ * 8,                                         \
                    &lds[bufi][kind][half][r2 * 4096 + tid * 8]);                     \
    }                                                                                 \
} while (0)

#define RD4_A(half_, mb)                                                              \
    _Pragma("unroll")                                                                 \
    for (int mm = 0; mm < 4; ++mm) {                                                  \
        const int row_ = ((mb) + mm) * 32 + wm * 16 + fr;                             \
        _Pragma("unroll")                                                             \
        for (int kk = 0; kk < 2; ++kk)                                                \
            Afr[mm][kk] = *(const bf16x8*)&lds[buf][0][half_]                         \
                [(row_ & 127) * 64 + (((kk * 4 + fq) ^ (row_ & 7)) * 8)];             \
    }

#define RD4_B(half_, nb)                                                              \
    _Pragma("unroll")                                                                 \
    for (int nn = 0; nn < 2; ++nn) {                                                  \
        const int row_ = ((nb) + nn) * 64 + wn * 16 + fr;                             \
        _Pragma("unroll")                                                             \
        for (int kk = 0; kk < 2; ++kk)                                                \
            Bfr[(nb) + nn][kk] = *(const bf16x8*)&lds[buf][1][half_]                  \
                [(row_ & 127) * 64 + (((kk * 4 + fq) ^ (row_ & 7)) * 8)];             \
    }

#define MFMAQ(mb, nb)                                                                 \
    __builtin_amdgcn_s_setprio(1);                                                    \
    _Pragma("unroll")                                                                 \
    for (int mm = 0; mm < 4; ++mm)                                                    \
        _Pragma("unroll")                                                             \
        for (int nn = 0; nn < 2; ++nn)                                                \
            _Pragma("unroll")                                                         \
            for (int kk = 0; kk < 2; ++kk)                                            \
                acc[(mb) + mm][(nb) + nn] = __builtin_amdgcn_mfma_f32_16x16x32_bf16(  \
                    Afr[mm][kk], Bfr[(nb) + nn][kk], acc[(mb) + mm][(nb) + nn], 0, 0, 0); \
    __builtin_amdgcn_s_setprio(0);

#define WAITV4  asm volatile("s_waitcnt vmcnt(10)" ::: "memory");                     \
                __builtin_amdgcn_sched_barrier(0);
#define BARR4   __builtin_amdgcn_s_barrier();                                         \
                __builtin_amdgcn_sched_barrier(0);

#define EPIX_M(mbase)                                                                 \
    {                                                                                 \
        _Pragma("unroll")                                                             \
        for (int mm = 0; mm < 8; ++mm) {                                              \
            _Pragma("unroll")                                                         \
            for (int rr = 0; rr < 4; ++rr) {                                          \
                int row_ = (mbase) + mm * 32 + wm * 16 + fq * 4 + rr;                 \
                int tt_ = row_ & 15, bb_ = row_ >> 4;                                 \
                ushort4 o_;                                                           \
                o_.x = f2h(acc[mm][0][rr]);                                           \
                o_.y = f2h(acc[mm][1][rr]);                                           \
                o_.z = f2h(acc[mm][2][rr]);                                           \
                o_.w = f2h(acc[mm][3][rr]);                                           \
                if (tt_ != 0) {                                                       \
                    *(ushort4*)(gx + (((size_t)tt_ * B_ + bb_) * H_ + j) * 4) = o_;   \
                } else {                                                              \
                    float gi_ = bi_ + h2f(o_.x);                                      \
                    float gg_ = bg_ + h2f(o_.z);                                      \
                    float go_ = bo_ + h2f(o_.w);                                      \
                    float cn_ = sigf(gi_) * tanhfast(gg_);                            \
                    float hv_ = sigf(go_) * tanhfast(cn_);                            \
                    size_t off_ = (size_t)bb_ * H_ + j;                               \
                    c[off_] = cn_;                                                    \
                    hbf0[off_] = f2bf(hv_);                                           \
                }                                                                     \
            }                                                                         \
        }                                                                             \
    }

__global__ __launch_bounds__(512, 2) void xgemm8m_kernel(
        const unsigned short* __restrict__ xbf,    // [32768][768] bf16 (m = b*16+t)
        const unsigned short* __restrict__ wih_t,  // [4096][768]  bf16 perm mode0
        unsigned short* __restrict__ gx,           // [16][2048][1024][4] f16
        const float* __restrict__ bias,
        float* __restrict__ c,                     // t=0 init
        unsigned short* __restrict__ hbf0) {       // h0
    __shared__ __align__(16) unsigned short lds[2][2][2][8192];   // 128 KB

    const int bid = blockIdx.x;               // 0..511
    const int xcd = bid & 7;
    const int i   = bid >> 3;                 // 0..63
    const int bn  = xcd * 2 + (i & 1);        // 0..15
    const int mg  = i >> 1;                   // 0..31
    const int bmb = mg * 1024;
    const int bn0 = bn * 256;

    const int tid = threadIdx.x;
    const int wid = tid >> 6, lane = tid & 63;
    const int wm = wid >> 2, wn = wid & 3;
    const int fr = lane & 15, fq = lane >> 4;

    const int j = bn * 64 + wn * 16 + fr;
    float bi_ = 0.f, bg_ = 0.f, bo_ = 0.f;
    if (fq == 0) {
        bi_ = bias[j]; bg_ = bias[2 * H_ + j]; bo_ = bias[3 * H_ + j];
    }

    f32x4 acc[8][4] = {};

    STAGE4(0, 0, 0, xbf, F_, bmb, 0);
    STAGE4(0, 1, 0, wih_t, F_, bn0, 0);
    STAGE4(0, 1, 1, wih_t, F_, bn0, 0);
    STAGE4(0, 0, 1, xbf, F_, bmb, 0);
    STAGE4(1, 0, 0, xbf, F_, bmb, 1);
    STAGE4(1, 1, 0, wih_t, F_, bn0, 1);
    STAGE4(1, 1, 1, wih_t, F_, bn0, 1);
    WAITV4; BARR4;

    for (int kt = 0; kt < 48; ++kt) {
        const int buf = kt & 1, nbuf = buf ^ 1;
        const int k1 = (kt + 1 < 48) ? kt + 1 : 47;
        const int k2 = (kt + 2 < 48) ? kt + 2 : 47;
        const int a1b = bmb + (k1 / 12) * 256, a1k = k1 % 12;
        const int a2b = bmb + (k2 / 12) * 256, a2k = k2 % 12;
        const int b2k = k2 % 12;
        bf16x8 Afr[4][2]; bf16x8 Bfr[4][2];
        /* ph0 */
        RD4_A(0, 0); RD4_B(0, 0);
        STAGE4(nbuf, 0, 1, xbf, F_, a1b, a1k);
        WAITV4; BARR4;
        MFMAQ(0, 0); BARR4;
        /* ph1 */
        RD4_B(1, 2);
        STAGE4(buf, 0, 0, xbf, F_, a2b, a2k);
        WAITV4; BARR4;
        MFMAQ(0, 2); BARR4;
        /* ph2 */
        RD4_A(1, 4);
        STAGE4(buf, 1, 0, wih_t, F_, bn0, b2k);
        BARR4;
        MFMAQ(4, 0); BARR4;
        /* ph3 */
        STAGE4(buf, 1, 1, wih_t, F_, bn0, b2k);
        WAITV4; BARR4;
        MFMAQ(4, 2); BARR4;
        if ((kt % 12) == 11) {
            EPIX_M(bmb + (kt / 12) * 256);
            #pragma unroll
            for (int mm = 0; mm < 8; ++mm)
                #pragma unroll
                for (int nf = 0; nf < 4; ++nf)
                    #pragma unroll
                    for (int q = 0; q < 4; ++q) acc[mm][nf][q] = 0.0f;
        }
    }
}

// ================================================================ recurrent step, 64x64 wave tiles
// BM=128, BN=128, BK=32, 256 thr = 4 waves (2m x 2n), wave tile 64x64.
//   m-frag mm (0..3): row = wm*64 + mm*16 + fr
//   n-frag nf (0..3): col = wn*64 + nf*16 + fr   (nf == gate, mode-1 perm)
// LDS 48KB: A[3][128][32], B[3][128][32]; slot(kt)=kt%3 -> 2 blocks/CU.
// Swizzle: 16B chunk index ^= (row>>2)&3 on gload source AND ds_read
//   (64-lane frag read covers the 16-row x 4-chunk span bijectively -> no
//   bank conflicts; 2-way max on staging).
// Single-phase K-tile (distance-2, proven family):
//   { 8 ds_read(kt) | 4 gload(kt+2 -> slot (kt+2)%3) | lgkm0 | 16 MFMA
//     | vmcnt(4) | bar }
// gx+c prefetched into registers at kt==29 (32 vm loads after stages);
// queue-sim waits: vmcnt(36) at kt in {29,30,31}, vmcnt(0) after loop.

#define STG_A32(slot, kt) do {                                                        \
    const int kel_ = (kt) * 32;                                                       \
    _Pragma("unroll")                                                                 \
    for (int r2 = 0; r2 < 2; ++r2) {                                                  \
        const int rih_ = r2 * 64 + (tid >> 2);                                        \
        const int ch_  = (tid & 3) ^ ((rih_ >> 2) & 3);                               \
        GLOAD_LDS16(hprev + (size_t)(bm0 + rih_) * H_ + kel_ + ch_ * 8,               \
                    &ldsA[slot][r2 * 2048 + tid * 8]);                                \
    }                                                                                 \
} while (0)

#define STG_B32(slot, kt) do {                                                        \
    const int kel_ = (kt) * 32;                                                       \
    _Pragma("unroll")                                                                 \
    for (int r2 = 0; r2 < 2; ++r2) {                                                  \
        const int rih_ = r2 * 64 + (tid >> 2);                                        \
        const int ch_  = (tid & 3) ^ ((rih_ >> 2) & 3);                               \
        GLOAD_LDS16(whh_t + (size_t)(bn0 + rih_) * H_ + kel_ + ch_ * 8,               \
                    &ldsB[slot][r2 * 2048 + tid * 8]);                                \
    }                                                                                 \
} while (0)

#define RD_A32(slot, AR)                                                              \
    _Pragma("unroll")                                                                 \
    for (int mm = 0; mm < 4; ++mm) {                                                  \
        const int row_ = wm * 64 + mm * 16 + fr;                                      \
        AR[mm] = *(const bf16x8*)&ldsA[slot]                                          \
            [row_ * 32 + ((fq ^ ((row_ >> 2) & 3)) * 8)];                             \
    }

#define RD_B32(slot, BF)                                                              \
    _Pragma("unroll")                                                                 \
    for (int nf = 0; nf < 4; ++nf) {                                                  \
        const int row_ = wn * 64 + nf * 16 + fr;                                      \
        BF[nf] = *(const bf16x8*)&ldsB[slot]                                          \
            [row_ * 32 + ((fq ^ ((row_ >> 2) & 3)) * 8)];                             \
    }

#define MFMA16T(AR, BF)                                                               \
    __builtin_amdgcn_s_setprio(1);                                                    \
    _Pragma("unroll")                                                                 \
    for (int mm = 0; mm < 4; ++mm)                                                    \
        _Pragma("unroll")                                                             \
        for (int nf = 0; nf < 4; ++nf)                                                \
            acc[mm][nf] = __builtin_amdgcn_mfma_f32_16x16x32_bf16(                    \
                AR[mm], BF[nf], acc[mm][nf], 0, 0, 0);                                \
    __builtin_amdgcn_s_setprio(0);

#define LGKM0 asm volatile("s_waitcnt lgkmcnt(0)" ::: "memory");
#define BARR  __builtin_amdgcn_s_barrier();

__global__ __launch_bounds__(256, 2) void lstm_step32_kernel(
        const unsigned short* __restrict__ hprev,  // [2048][1024] bf16
        const unsigned short* __restrict__ whh_t,  // [4096][1024] bf16 perm mode1
        const unsigned short* __restrict__ gx,     // [16][2048][1024][4] f16
        const float* __restrict__ bias,            // [4096] original order
        float* __restrict__ c,                     // [2048][1024] f32 r/w
        unsigned short* __restrict__ hnext,        // [2048][1024] bf16
        float* __restrict__ hout,                  // [2048][1024] f32 (last)
        int t, int last) {
    __shared__ __align__(16) unsigned short ldsA[3][4096];   // 24 KB
    __shared__ __align__(16) unsigned short ldsB[3][4096];   // 24 KB

    // XCD-aware: xcd owns 4 bn -> Whh panel 1MB L2-resident
    const int bid = blockIdx.x;               // 0..511
    const int xcd = bid & 7;
    const int i   = bid >> 3;                 // 0..63
    const int bn  = xcd * 4 + (i & 3);        // 0..31
    const int bm  = i >> 2;                   // 0..15
    const int bm0 = bm * 128, bn0 = bn * 128;

    const int tid = threadIdx.x;
    const int wid = tid >> 6, lane = tid & 63;
    const int wm = wid >> 1, wn = wid & 1;
    const int fr = lane & 15, fq = lane >> 4;

    const int j = (bn * 2 + wn) * 16 + fr;    // this thread's hidden unit
    const float bi = bias[j];
    const float bf = bias[H_ + j];
    const float bg = bias[2 * H_ + j];
    const float bo = bias[3 * H_ + j];

    f32x4 acc[4][4] = {};
    ushort4 gpre[4][4];
    float   cpre[4][4];

    // prologue: tiles 0,1 (8 loads); vmcnt(4) forces tile 0
    STG_A32(0, 0); STG_B32(0, 0);
    STG_A32(1, 1); STG_B32(1, 1);
    asm volatile("s_waitcnt vmcnt(4)" ::: "memory");
    BARR;

    for (int kt = 0; kt < 32; ++kt) {
        const int s_  = kt % 3;
        const int s2_ = (kt + 2) % 3;
        const int k2_ = (kt + 2 < 32) ? kt + 2 : 31;
        bf16x8 Am[4], Bf[4];
        RD_A32(s_, Am);
        RD_B32(s_, Bf);
        STG_A32(s2_, k2_);
        STG_B32(s2_, k2_);
        if (kt == 29) {
            // prefetch gx + c into registers (32 vm loads, after stages)
            #pragma unroll
            for (int mm = 0; mm < 4; ++mm)
                #pragma unroll
                for (int rr = 0; rr < 4; ++rr) {
                    int row_ = bm0 + wm * 64 + mm * 16 + fq * 4 + rr;
                    gpre[mm][rr] = *(const ushort4*)(gx + (((size_t)t * B_ + row_) * H_ + j) * 4);
                    cpre[mm][rr] = c[(size_t)row_ * H_ + j];
                }
        }
        LGKM0;
        MFMA16T(Am, Bf);
        if (kt >= 29)
            asm volatile("s_waitcnt vmcnt(36)" ::: "memory");
        else
            asm volatile("s_waitcnt vmcnt(4)" ::: "memory");
        BARR;
    }
    asm volatile("s_waitcnt vmcnt(0)" ::: "memory");

    // fused LSTM-cell epilogue (gates from acc + gpre; c from cpre)
    #pragma unroll
    for (int mm = 0; mm < 4; ++mm) {
        #pragma unroll
        for (int rr = 0; rr < 4; ++rr) {
            int row_ = bm0 + wm * 64 + mm * 16 + fq * 4 + rr;
            ushort4 g4 = gpre[mm][rr];
            float gi = acc[mm][0][rr] + bi + h2f(g4.x);
            float gf = acc[mm][1][rr] + bf + h2f(g4.y);
            float gg = acc[mm][2][rr] + bg + h2f(g4.z);
            float go = acc[mm][3][rr] + bo + h2f(g4.w);
            float cn = sigf(gf) * cpre[mm][rr] + sigf(gi) * tanhfast(gg);
            float hv = sigf(go) * tanhfast(cn);
            size_t off = (size_t)row_ * H_ + j;
            c[off] = cn;
            hnext[off] = f2bf(hv);
            if (last) hout[off] = hv;
        }
    }
}

// ---------------------------------------------------------------- launch

extern "C" void kernel_launch(void* const* d_in, const int* in_sizes, int n_in,
                              void* d_out, int out_size, void* d_ws, size_t ws_size,
                              hipStream_t stream) {
    const float* x    = (const float*)d_in[0];   // [B,T,F]
    const float* Wih  = (const float*)d_in[1];   // [F,4H]
    const float* Whh  = (const float*)d_in[2];   // [H,4H]
    const float* bias = (const float*)d_in[3];   // [4H]
    float* out = (float*)d_out;                  // [B,H] flat

    char* ws = (char*)d_ws;
    unsigned short* xbf   = (unsigned short*)(ws);               // 50,331,648 B
    unsigned short* wih_t = (unsigned short*)(ws + 50331648);    //  6,291,456
    unsigned short* whh_t = (unsigned short*)(ws + 56623104);    //  8,388,608
    unsigned short* hbf0  = (unsigned short*)(ws + 65011712);    //  4,194,304
    unsigned short* hbf1  = (unsigned short*)(ws + 69206016);    //  4,194,304
    float*          c     = (float*)(ws + 73400320);             //  8,388,608
    unsigned short* gx    = (unsigned short*)(ws + 81788928);    // 268,435,456
    // total 350,224,384 B <= ws_size

    // merged prep: convert x + both W transposes in one launch
    hipLaunchKernelGGL(prep_kernel, dim3(24576 + 3072 + 4096), dim3(256), 0, stream,
                       x, xbf, Wih, wih_t, Whh, whh_t);

    // input projection (all t) + fused t=0 cell, M-merged x4
    hipLaunchKernelGGL(xgemm8m_kernel, dim3(512), dim3(512), 0, stream,
                       xbf, wih_t, gx, bias, c, hbf0);

    // t = 1..15: recurrent GEMM + fused cell, 64x64 wave tiles, 2 blocks/CU
    for (int t = 1; t < T_; ++t) {
        unsigned short* hr = (t & 1) ? hbf0 : hbf1;
        unsigned short* hw = (t & 1) ? hbf1 : hbf0;
        hipLaunchKernelGGL(lstm_step32_kernel, dim3(512), dim3(256), 0, stream,
                           hr, whh_t, gx, bias, c, hw, out, t, (t == T_ - 1) ? 1 : 0);
    }
}

// Round 15
// 724.125 us; speedup vs baseline: 1.1560x; 1.1560x over previous
//
#include <hip/hip_runtime.h>
#include <hip/hip_bf16.h>
#include <stdint.h>

#define B_  2048
#define T_  16
#define F_  768
#define H_  1024
#define G4_ 4096   // 4*H

typedef __attribute__((ext_vector_type(8))) __bf16 bf16x8;
typedef __attribute__((ext_vector_type(4))) float  f32x4;

static __device__ __forceinline__ unsigned short f2bf(float f) {
    union { float f; uint32_t u; } v; v.f = f;
    uint32_t u = v.u;
    uint32_t r = (u + 0x7fffu + ((u >> 16) & 1u)) >> 16;   // RNE
    return (unsigned short)r;
}
static __device__ __forceinline__ unsigned short f2h(float f) {
    union { _Float16 h; unsigned short u; } v; v.h = (_Float16)f; return v.u;
}
static __device__ __forceinline__ float h2f(unsigned short u) {
    union { _Float16 h; unsigned short u; } v; v.u = u; return (float)v.h;
}
static __device__ __forceinline__ float sigf(float x) {
    return 1.0f / (1.0f + __expf(-x));
}
static __device__ __forceinline__ float tanhfast(float x) {
    return 2.0f / (1.0f + __expf(-2.0f * x)) - 1.0f;
}

#define GLOAD_LDS16(gsrc, ldst)                                                       \
    __builtin_amdgcn_global_load_lds((const __attribute__((address_space(1))) void*)(gsrc), \
                                     (__attribute__((address_space(3))) void*)(ldst), \
                                     16, 0, 0)

// ---------------------------------------------------------------- merged prep kernel
// (round-13 verbatim)

__global__ void prep_kernel(const float* __restrict__ x, unsigned short* __restrict__ xbf,
                            const float* __restrict__ Wih, unsigned short* __restrict__ wih_t,
                            const float* __restrict__ Whh, unsigned short* __restrict__ whh_t) {
    const int bid = blockIdx.x;
    const int tid = threadIdx.x;
    if (bid < 24576) {
        int idx = bid * 256 + tid;      // B*T*F/4 float4
        float4 v = *(const float4*)(x + (size_t)idx * 4);
        ushort4 o;
        o.x = f2bf(v.x); o.y = f2bf(v.y); o.z = f2bf(v.z); o.w = f2bf(v.w);
        *(ushort4*)(xbf + (size_t)idx * 4) = o;
        return;
    }
    __shared__ float tile[32][33];
    const float* w;
    unsigned short* wt;
    int K, mode, idx;
    if (bid < 24576 + 3072) { w = Wih; wt = wih_t; K = F_; mode = 0; idx = bid - 24576; }
    else                    { w = Whh; wt = whh_t; K = H_; mode = 1; idx = bid - 27648; }
    int nb = (idx & 127) * 32;          // over 4096
    int kb = (idx >> 7) * 32;           // over K
    int tx = tid & 31, ty = tid >> 5;   // 32 x 8
    #pragma unroll
    for (int i = 0; i < 32; i += 8)
        tile[ty + i][tx] = w[(size_t)(kb + ty + i) * G4_ + nb + tx];
    __syncthreads();
    #pragma unroll
    for (int i = 0; i < 32; i += 8) {
        int n = nb + ty + i;
        int g = n >> 10;
        int j = n & 1023;
        int np = mode ? ((j >> 4) * 64 + g * 16 + (j & 15))
                      : ((j >> 6) * 256 + g * 64 + ((j >> 4) & 3) * 16 + (j & 15));
        wt[(size_t)np * K + kb + tx] = f2bf(tile[tx][ty + i]);
    }
}

// ================================================================ 8-phase 256^2 xgemm, M-merged x4
// (round-13 verbatim; measured 219 us @ MfmaUtil 41%)

#define STAGE4(bufi, kind, half, gbase, ld, rowbase, kt) do {                         \
    const int kel_ = (kt) * 64;                                                       \
    _Pragma("unroll")                                                                 \
    for (int r2 = 0; r2 < 2; ++r2) {                                                  \
        const int rih_ = r2 * 64 + (tid >> 3);                                        \
        const int ch_  = (tid & 7) ^ (rih_ & 7);                                      \
        GLOAD_LDS16((gbase) + (size_t)((rowbase) + (half) * 128 + rih_) * (ld)        \
                            + kel_ + ch_ * 8,                                         \
                    &lds[bufi][kind][half][r2 * 4096 + tid * 8]);                     \
    }                                                                                 \
} while (0)

#define RD4_A(half_, mb)                                                              \
    _Pragma("unroll")                                                                 \
    for (int mm = 0; mm < 4; ++mm) {                                                  \
        const int row_ = ((mb) + mm) * 32 + wm * 16 + fr;                             \
        _Pragma("unroll")                                                             \
        for (int kk = 0; kk < 2; ++kk)                                                \
            Afr[mm][kk] = *(const bf16x8*)&lds[buf][0][half_]                         \
                [(row_ & 127) * 64 + (((kk * 4 + fq) ^ (row_ & 7)) * 8)];             \
    }

#define RD4_B(half_, nb)                                                              \
    _Pragma("unroll")                                                                 \
    for (int nn = 0; nn < 2; ++nn) {                                                  \
        const int row_ = ((nb) + nn) * 64 + wn * 16 + fr;                             \
        _Pragma("unroll")                                                             \
        for (int kk = 0; kk < 2; ++kk)                                                \
            Bfr[(nb) + nn][kk] = *(const bf16x8*)&lds[buf][1][half_]                  \
                [(row_ & 127) * 64 + (((kk * 4 + fq) ^ (row_ & 7)) * 8)];             \
    }

#define MFMAQ(mb, nb)                                                                 \
    __builtin_amdgcn_s_setprio(1);                                                    \
    _Pragma("unroll")                                                                 \
    for (int mm = 0; mm < 4; ++mm)                                                    \
        _Pragma("unroll")                                                             \
        for (int nn = 0; nn < 2; ++nn)                                                \
            _Pragma("unroll")                                                         \
            for (int kk = 0; kk < 2; ++kk)                                            \
                acc[(mb) + mm][(nb) + nn] = __builtin_amdgcn_mfma_f32_16x16x32_bf16(  \
                    Afr[mm][kk], Bfr[(nb) + nn][kk], acc[(mb) + mm][(nb) + nn], 0, 0, 0); \
    __builtin_amdgcn_s_setprio(0);

#define WAITV4  asm volatile("s_waitcnt vmcnt(10)" ::: "memory");                     \
                __builtin_amdgcn_sched_barrier(0);
#define BARR4   __builtin_amdgcn_s_barrier();                                         \
                __builtin_amdgcn_sched_barrier(0);

#define EPIX_M(mbase)                                                                 \
    {                                                                                 \
        _Pragma("unroll")                                                             \
        for (int mm = 0; mm < 8; ++mm) {                                              \
            _Pragma("unroll")                                                         \
            for (int rr = 0; rr < 4; ++rr) {                                          \
                int row_ = (mbase) + mm * 32 + wm * 16 + fq * 4 + rr;                 \
                int tt_ = row_ & 15, bb_ = row_ >> 4;                                 \
                ushort4 o_;                                                           \
                o_.x = f2h(acc[mm][0][rr]);                                           \
                o_.y = f2h(acc[mm][1][rr]);                                           \
                o_.z = f2h(acc[mm][2][rr]);                                           \
                o_.w = f2h(acc[mm][3][rr]);                                           \
                if (tt_ != 0) {                                                       \
                    *(ushort4*)(gx + (((size_t)tt_ * B_ + bb_) * H_ + j) * 4) = o_;   \
                } else {                                                              \
                    float gi_ = bi_ + h2f(o_.x);                                      \
                    float gg_ = bg_ + h2f(o_.z);                                      \
                    float go_ = bo_ + h2f(o_.w);                                      \
                    float cn_ = sigf(gi_) * tanhfast(gg_);                            \
                    float hv_ = sigf(go_) * tanhfast(cn_);                            \
                    size_t off_ = (size_t)bb_ * H_ + j;                               \
                    c[off_] = cn_;                                                    \
                    hbf0[off_] = f2bf(hv_);                                           \
                }                                                                     \
            }                                                                         \
        }                                                                             \
    }

__global__ __launch_bounds__(512, 2) void xgemm8m_kernel(
        const unsigned short* __restrict__ xbf,    // [32768][768] bf16 (m = b*16+t)
        const unsigned short* __restrict__ wih_t,  // [4096][768]  bf16 perm mode0
        unsigned short* __restrict__ gx,           // [16][2048][1024][4] f16
        const float* __restrict__ bias,
        float* __restrict__ c,                     // t=0 init
        unsigned short* __restrict__ hbf0) {       // h0
    __shared__ __align__(16) unsigned short lds[2][2][2][8192];   // 128 KB

    const int bid = blockIdx.x;               // 0..511
    const int xcd = bid & 7;
    const int i   = bid >> 3;                 // 0..63
    const int bn  = xcd * 2 + (i & 1);        // 0..15
    const int mg  = i >> 1;                   // 0..31
    const int bmb = mg * 1024;
    const int bn0 = bn * 256;

    const int tid = threadIdx.x;
    const int wid = tid >> 6, lane = tid & 63;
    const int wm = wid >> 2, wn = wid & 3;
    const int fr = lane & 15, fq = lane >> 4;

    const int j = bn * 64 + wn * 16 + fr;
    float bi_ = 0.f, bg_ = 0.f, bo_ = 0.f;
    if (fq == 0) {
        bi_ = bias[j]; bg_ = bias[2 * H_ + j]; bo_ = bias[3 * H_ + j];
    }

    f32x4 acc[8][4] = {};

    STAGE4(0, 0, 0, xbf, F_, bmb, 0);
    STAGE4(0, 1, 0, wih_t, F_, bn0, 0);
    STAGE4(0, 1, 1, wih_t, F_, bn0, 0);
    STAGE4(0, 0, 1, xbf, F_, bmb, 0);
    STAGE4(1, 0, 0, xbf, F_, bmb, 1);
    STAGE4(1, 1, 0, wih_t, F_, bn0, 1);
    STAGE4(1, 1, 1, wih_t, F_, bn0, 1);
    WAITV4; BARR4;

    for (int kt = 0; kt < 48; ++kt) {
        const int buf = kt & 1, nbuf = buf ^ 1;
        const int k1 = (kt + 1 < 48) ? kt + 1 : 47;
        const int k2 = (kt + 2 < 48) ? kt + 2 : 47;
        const int a1b = bmb + (k1 / 12) * 256, a1k = k1 % 12;
        const int a2b = bmb + (k2 / 12) * 256, a2k = k2 % 12;
        const int b2k = k2 % 12;
        bf16x8 Afr[4][2]; bf16x8 Bfr[4][2];
        /* ph0 */
        RD4_A(0, 0); RD4_B(0, 0);
        STAGE4(nbuf, 0, 1, xbf, F_, a1b, a1k);
        WAITV4; BARR4;
        MFMAQ(0, 0); BARR4;
        /* ph1 */
        RD4_B(1, 2);
        STAGE4(buf, 0, 0, xbf, F_, a2b, a2k);
        WAITV4; BARR4;
        MFMAQ(0, 2); BARR4;
        /* ph2 */
        RD4_A(1, 4);
        STAGE4(buf, 1, 0, wih_t, F_, bn0, b2k);
        BARR4;
        MFMAQ(4, 0); BARR4;
        /* ph3 */
        STAGE4(buf, 1, 1, wih_t, F_, bn0, b2k);
        WAITV4; BARR4;
        MFMAQ(4, 2); BARR4;
        if ((kt % 12) == 11) {
            EPIX_M(bmb + (kt / 12) * 256);
            #pragma unroll
            for (int mm = 0; mm < 8; ++mm)
                #pragma unroll
                for (int nf = 0; nf < 4; ++nf)
                    #pragma unroll
                    for (int q = 0; q < 4; ++q) acc[mm][nf][q] = 0.0f;
        }
    }
}

// ================================================================ recurrent step
// Round-10 panel-merged kernel with DISTANCE-3 A staging (4 A slots).
// BM=64, BN=128(x2 panels), BK=64, 256 thr = 4 waves; LDS 80KB -> 2 blocks/CU.
// Per kt: { 12 ds_read(kt: A slot kt%4, B slot kt%3)
//           | stage A(kt+3)->slot (kt+3)%4 (tile (kt+3)&15; A repeats/panel)
//           | stage B(kt+2)->slot (kt+2)%3
//           | [gx+c reg prefetch at kt=13/29] | lgkm0 | 16 MFMA
//           | vmcnt(22 if kt in {13,14,29,30} else 6) | bar }
// Queue-sim: end-of-kt vmcnt(6) keeps newest {A(kt+3)x2, B(kt+2)x4}, forcing
// B(kt+1) and A(kt+2) -> A slack 2.3 tile-times (covers h's L2-miss latency),
// B slack 1.3 (Whh L2-resident).  Slot-liveness: A slot (kt+3)%4 holds tile
// kt-1, readers retired at kt-1's lgkm0+barrier.  vmcnt never 0 in loop.

#define STA6(slot, kt) do {                                                           \
    const int kel_ = (kt) * 64;                                                       \
    _Pragma("unroll")                                                                 \
    for (int r2 = 0; r2 < 2; ++r2) {                                                  \
        const int rih_ = r2 * 32 + (tid >> 3);                                        \
        const int ch_  = (tid & 7) ^ (rih_ & 7);                                      \
        GLOAD_LDS16(hprev + (size_t)(bm0 + rih_) * H_ + kel_ + ch_ * 8,               \
                    &ldsA[slot][r2 * 2048 + tid * 8]);                                \
    }                                                                                 \
} while (0)

#define STB6(slot, rowbase, kt) do {                                                  \
    const int kel_ = (kt) * 64;                                                       \
    _Pragma("unroll")                                                                 \
    for (int r4 = 0; r4 < 4; ++r4) {                                                  \
        const int rih_ = r4 * 32 + (tid >> 3);                                        \
        const int ch_  = (tid & 7) ^ (rih_ & 7);                                      \
        GLOAD_LDS16(whh_t + (size_t)((rowbase) + rih_) * H_ + kel_ + ch_ * 8,         \
                    &ldsB[slot][r4 * 2048 + tid * 8]);                                \
    }                                                                                 \
} while (0)

#define RD_A6(slot, AR)                                                               \
    _Pragma("unroll")                                                                 \
    for (int mm = 0; mm < 2; ++mm) {                                                  \
        const int row_ = wm * 32 + mm * 16 + fr;                                      \
        _Pragma("unroll")                                                             \
        for (int kk = 0; kk < 2; ++kk)                                                \
            AR[mm][kk] = *(const bf16x8*)&ldsA[slot]                                  \
                [row_ * 64 + (((kk * 4 + fq) ^ (row_ & 7)) * 8)];                     \
    }

#define RD_B6(slot, BF)                                                               \
    _Pragma("unroll")                                                                 \
    for (int nf = 0; nf < 4; ++nf) {                                                  \
        const int rowb_ = wn * 64 + nf * 16 + fr;                                     \
        _Pragma("unroll")                                                             \
        for (int kk = 0; kk < 2; ++kk)                                                \
            BF[nf][kk] = *(const bf16x8*)&ldsB[slot]                                  \
                [rowb_ * 64 + (((kk * 4 + fq) ^ (rowb_ & 7)) * 8)];                   \
    }

#define MFMA16S(AR, BF)                                                               \
    __builtin_amdgcn_s_setprio(1);                                                    \
    _Pragma("unroll")                                                                 \
    for (int mm = 0; mm < 2; ++mm)                                                    \
        _Pragma("unroll")                                                             \
        for (int nf = 0; nf < 4; ++nf)                                                \
            _Pragma("unroll")                                                         \
            for (int kk = 0; kk < 2; ++kk)                                            \
                acc[mm][nf] = __builtin_amdgcn_mfma_f32_16x16x32_bf16(                \
                    AR[mm][kk], BF[nf][kk], acc[mm][nf], 0, 0, 0);                    \
    __builtin_amdgcn_s_setprio(0);

#define LGKM0 asm volatile("s_waitcnt lgkmcnt(0)" ::: "memory");
#define BARR  __builtin_amdgcn_s_barrier();

__global__ __launch_bounds__(256, 2) void lstm_step_d3_kernel(
        const unsigned short* __restrict__ hprev,  // [2048][1024] bf16
        const unsigned short* __restrict__ whh_t,  // [4096][1024] bf16 perm mode1
        const unsigned short* __restrict__ gx,     // [16][2048][1024][4] f16
        const float* __restrict__ bias,            // [4096] original order
        float* __restrict__ c,                     // [2048][1024] f32 r/w
        unsigned short* __restrict__ hnext,        // [2048][1024] bf16
        float* __restrict__ hout,                  // [2048][1024] f32 (last)
        int t, int last) {
    __shared__ __align__(16) unsigned short ldsA[4][4096];   // 32 KB (4 slots)
    __shared__ __align__(16) unsigned short ldsB[3][8192];   // 48 KB

    const int bid = blockIdx.x;               // 0..511
    const int xcd = bid & 7;
    const int i   = bid >> 3;                 // 0..63
    const int pair = i & 1;
    const int bm  = i >> 1;                   // 0..31
    const int bn_base = xcd * 4 + pair * 2;   // panels bn_base, bn_base+1
    const int bm0 = bm * 64;

    const int tid = threadIdx.x;
    const int wid = tid >> 6, lane = tid & 63;
    const int wm = wid >> 1, wn = wid & 1;
    const int fr = lane & 15, fq = lane >> 4;

    const int j0 = (bn_base * 2 + wn) * 16 + fr;
    const int j1 = ((bn_base + 1) * 2 + wn) * 16 + fr;
    const float bi0 = bias[j0], bf0 = bias[H_ + j0], bg0 = bias[2 * H_ + j0], bo0 = bias[3 * H_ + j0];
    const float bi1 = bias[j1], bf1 = bias[H_ + j1], bg1 = bias[2 * H_ + j1], bo1 = bias[3 * H_ + j1];

    f32x4 acc[2][4] = {};
    ushort4 gpre[2][4];
    float   cpre[2][4];

    // prologue: A tiles 0,1,2 (slots 0,1,2) + B tiles 0,1 (slots 0,1)
    STA6(0, 0); STB6(0, bn_base * 128, 0);
    STA6(1, 1); STB6(1, bn_base * 128, 1);
    STA6(2, 2);
    asm volatile("s_waitcnt vmcnt(8)" ::: "memory");   // forces A0,B0
    BARR;

    for (int kt = 0; kt < 32; ++kt) {
        const int sA_  = kt & 3;                               // A slot (4)
        const int sB_  = kt % 3;                               // B slot (3)
        const int sA3_ = (kt + 3) & 3;
        const int sB2_ = (kt + 2) % 3;
        const int a3   = (kt + 3) & 15;                        // A repeats per panel
        const int k2   = (kt + 2 < 32) ? kt + 2 : 31;
        const int brb2 = (bn_base + (k2 >> 4)) * 128;          // B base of staged tile
        bf16x8 Am[2][2], Bf[4][2];
        RD_A6(sA_, Am);
        RD_B6(sB_, Bf);
        STA6(sA3_, a3);
        STB6(sB2_, brb2, k2 & 15);
        if (kt == 13 || kt == 29) {
            const int p_ = kt >> 4;
            const int jp_ = p_ ? j1 : j0;
            #pragma unroll
            for (int mm = 0; mm < 2; ++mm)
                #pragma unroll
                for (int rr = 0; rr < 4; ++rr) {
                    int row_ = bm0 + wm * 32 + mm * 16 + fq * 4 + rr;
                    gpre[mm][rr] = *(const ushort4*)(gx + (((size_t)t * B_ + row_) * H_ + jp_) * 4);
                    cpre[mm][rr] = c[(size_t)row_ * H_ + jp_];
                }
        }
        LGKM0;
        MFMA16S(Am, Bf);
        if (kt == 13 || kt == 14 || kt == 29 || kt == 30)
            asm volatile("s_waitcnt vmcnt(22)" ::: "memory");
        else
            asm volatile("s_waitcnt vmcnt(6)" ::: "memory");
        BARR;
        if (kt == 15) {
            #pragma unroll
            for (int mm = 0; mm < 2; ++mm) {
                #pragma unroll
                for (int rr = 0; rr < 4; ++rr) {
                    int row_ = bm0 + wm * 32 + mm * 16 + fq * 4 + rr;
                    ushort4 g4 = gpre[mm][rr];
                    float gi = acc[mm][0][rr] + bi0 + h2f(g4.x);
                    float gf = acc[mm][1][rr] + bf0 + h2f(g4.y);
                    float gg = acc[mm][2][rr] + bg0 + h2f(g4.z);
                    float go = acc[mm][3][rr] + bo0 + h2f(g4.w);
                    float cn = sigf(gf) * cpre[mm][rr] + sigf(gi) * tanhfast(gg);
                    float hv = sigf(go) * tanhfast(cn);
                    size_t off = (size_t)row_ * H_ + j0;
                    c[off] = cn;
                    hnext[off] = f2bf(hv);
                    if (last) hout[off] = hv;
                }
            }
            #pragma unroll
            for (int mm = 0; mm < 2; ++mm)
                #pragma unroll
                for (int nf = 0; nf < 4; ++nf)
                    #pragma unroll
                    for (int q = 0; q < 4; ++q) acc[mm][nf][q] = 0.0f;
        }
    }

    // panel-1 epilogue (prefetches forced by end-of-kt-31 vmcnt(6))
    #pragma unroll
    for (int mm = 0; mm < 2; ++mm) {
        #pragma unroll
        for (int rr = 0; rr < 4; ++rr) {
            int row_ = bm0 + wm * 32 + mm * 16 + fq * 4 + rr;
            ushort4 g4 = gpre[mm][rr];
            float gi = acc[mm][0][rr] + bi1 + h2f(g4.x);
            float gf = acc[mm][1][rr] + bf1 + h2f(g4.y);
            float gg = acc[mm][2][rr] + bg1 + h2f(g4.z);
            float go = acc[mm][3][rr] + bo1 + h2f(g4.w);
            float cn = sigf(gf) * cpre[mm][rr] + sigf(gi) * tanhfast(gg);
            float hv = sigf(go) * tanhfast(cn);
            size_t off = (size_t)row_ * H_ + j1;
            c[off] = cn;
            hnext[off] = f2bf(hv);
            if (last) hout[off] = hv;
        }
    }
}

// ---------------------------------------------------------------- launch

extern "C" void kernel_launch(void* const* d_in, const int* in_sizes, int n_in,
                              void* d_out, int out_size, void* d_ws, size_t ws_size,
                              hipStream_t stream) {
    const float* x    = (const float*)d_in[0];   // [B,T,F]
    const float* Wih  = (const float*)d_in[1];   // [F,4H]
    const float* Whh  = (const float*)d_in[2];   // [H,4H]
    const float* bias = (const float*)d_in[3];   // [4H]
    float* out = (float*)d_out;                  // [B,H] flat

    char* ws = (char*)d_ws;
    unsigned short* xbf   = (unsigned short*)(ws);               // 50,331,648 B
    unsigned short* wih_t = (unsigned short*)(ws + 50331648);    //  6,291,456
    unsigned short* whh_t = (unsigned short*)(ws + 56623104);    //  8,388,608
    unsigned short* hbf0  = (unsigned short*)(ws + 65011712);    //  4,194,304
    unsigned short* hbf1  = (unsigned short*)(ws + 69206016);    //  4,194,304
    float*          c     = (float*)(ws + 73400320);             //  8,388,608
    unsigned short* gx    = (unsigned short*)(ws + 81788928);    // 268,435,456
    // total 350,224,384 B <= ws_size

    // merged prep: convert x + both W transposes in one launch
    hipLaunchKernelGGL(prep_kernel, dim3(24576 + 3072 + 4096), dim3(256), 0, stream,
                       x, xbf, Wih, wih_t, Whh, whh_t);

    // input projection (all t) + fused t=0 cell, M-merged x4
    hipLaunchKernelGGL(xgemm8m_kernel, dim3(512), dim3(512), 0, stream,
                       xbf, wih_t, gx, bias, c, hbf0);

    // t = 1..15: recurrent GEMM + fused cell, distance-3 A staging, 2 blocks/CU
    for (int t = 1; t < T_; ++t) {
        unsigned short* hr = (t & 1) ? hbf0 : hbf1;
        unsigned short* hw = (t & 1) ? hbf1 : hbf0;
        hipLaunchKernelGGL(lstm_step_d3_kernel, dim3(512), dim3(256), 0, stream,
                           hr, whh_t, gx, bias, c, hw, out, t, (t == T_ - 1) ? 1 : 0);
    }
}